// Round 1
// baseline (620.129 us; speedup 1.0000x reference)
//
#include <hip/hip_runtime.h>
#include <hip/hip_bf16.h>

// ---------------------------------------------------------------------------
// Feature_Decoder: out = LN(leaky_relu(inp @ Wf^T + bf) * (static @ Wc^T + bc))
// B=32, N=2048, F=512, K_city=256, D=1024.  M = B*N = 65536.
//   k1 convw: W_feat fp32 -> bf16 (ws, 1 MB)
//   k2 city : c = static @ Wc^T + bc, MFMA bf16, store bf16 (ws, 4 MB)
//   k3 feat : BM=64 x full-D MFMA GEMM, ZERO-LDS / ZERO-BARRIER K-loop:
//             B frags read directly from L2-resident Wf (1 MB), A frags read
//             fp32 and converted in-register (v_cvt_pk_bf16_f32). Barriers
//             only in the fused bias+leaky+gate+LayerNorm epilogue.
// ---------------------------------------------------------------------------

typedef __attribute__((ext_vector_type(8))) short short8;
typedef __attribute__((ext_vector_type(4))) float f32x4;

__device__ __forceinline__ unsigned short f2bf(float f) {
    unsigned int u = __float_as_uint(f);
    return (unsigned short)((u + 0x7FFFu + ((u >> 16) & 1u)) >> 16);   // RNE
}
__device__ __forceinline__ float b2f(unsigned short h) {
    return __uint_as_float(((unsigned int)h) << 16);
}

// ---------------------------------------------------------------------------
// k1: W_feat [1024,512] fp32 -> bf16
// ---------------------------------------------------------------------------
__global__ __launch_bounds__(256) void convw_kernel(
    const float* __restrict__ w, unsigned short* __restrict__ o)
{
    int i = (blockIdx.x * 256 + threadIdx.x) * 4;
    float4 v = *(const float4*)(w + i);
    uint2 p;
    p.x = (unsigned)f2bf(v.x) | ((unsigned)f2bf(v.y) << 16);
    p.y = (unsigned)f2bf(v.z) | ((unsigned)f2bf(v.w) << 16);
    *(uint2*)(o + i) = p;
}

// ---------------------------------------------------------------------------
// k2: c[n,d] = dot(static[n,:], Wc[d,:]) + bc[d]  via MFMA bf16.
// Tile 64(n) x 128(d) per block, whole K=256 staged in LDS (fp32->bf16 inline).
// Grid 32 x 8 = 256 blocks = exactly 1 per CU. 256 threads = 4 waves.
// ---------------------------------------------------------------------------
__global__ __launch_bounds__(256) void city_kernel(
    const float* __restrict__ st,    // [2048,256]
    const float* __restrict__ Wc,    // [1024,256]
    const float* __restrict__ bc,    // [1024]
    unsigned short* __restrict__ cg) // bf16 [2048,1024]
{
    __shared__ __align__(16) unsigned short Sa[64 * 264];
    __shared__ __align__(16) unsigned short Sb[128 * 264];
    const int t  = threadIdx.x;
    const int n0 = blockIdx.x << 6;
    const int d0 = blockIdx.y << 7;

    #pragma unroll
    for (int i = 0; i < 16; ++i) {
        int idx = (i << 8) + t;
        int row = idx >> 6, kq = (idx & 63) << 2;
        float4 v = *(const float4*)(st + (size_t)(n0 + row) * 256 + kq);
        uint2 p;
        p.x = (unsigned)f2bf(v.x) | ((unsigned)f2bf(v.y) << 16);
        p.y = (unsigned)f2bf(v.z) | ((unsigned)f2bf(v.w) << 16);
        *(uint2*)(Sa + row * 264 + kq) = p;
    }
    #pragma unroll
    for (int i = 0; i < 32; ++i) {
        int idx = (i << 8) + t;
        int row = idx >> 6, kq = (idx & 63) << 2;
        float4 v = *(const float4*)(Wc + (size_t)(d0 + row) * 256 + kq);
        uint2 p;
        p.x = (unsigned)f2bf(v.x) | ((unsigned)f2bf(v.y) << 16);
        p.y = (unsigned)f2bf(v.z) | ((unsigned)f2bf(v.w) << 16);
        *(uint2*)(Sb + row * 264 + kq) = p;
    }
    __syncthreads();

    const int wv = t >> 6;            // wave 0..3 -> d strip wv*32
    const int cl = t & 15, q = (t >> 4) & 3;
    f32x4 acc[4][2];
    #pragma unroll
    for (int rt = 0; rt < 4; ++rt)
        #pragma unroll
        for (int ct = 0; ct < 2; ++ct) acc[rt][ct] = (f32x4)0.f;

    #pragma unroll
    for (int ks = 0; ks < 8; ++ks) {
        short8 a[4];
        #pragma unroll
        for (int rt = 0; rt < 4; ++rt)
            a[rt] = *(const short8*)(Sa + ((rt << 4) + cl) * 264 + (ks << 5) + (q << 3));
        #pragma unroll
        for (int ct = 0; ct < 2; ++ct) {
            short8 bf8 = *(const short8*)(Sb + ((wv << 5) + (ct << 4) + cl) * 264 + (ks << 5) + (q << 3));
            #pragma unroll
            for (int rt = 0; rt < 4; ++rt)
                acc[rt][ct] = __builtin_amdgcn_mfma_f32_16x16x32_bf16(a[rt], bf8, acc[rt][ct], 0, 0, 0);
        }
    }
    #pragma unroll
    for (int ct = 0; ct < 2; ++ct) {
        const int d = d0 + (wv << 5) + (ct << 4) + cl;
        const float bcv = bc[d];
        #pragma unroll
        for (int rt = 0; rt < 4; ++rt)
            #pragma unroll
            for (int rr = 0; rr < 4; ++rr) {
                const int row = (rt << 4) + (q << 2) + rr;   // C/D: row=(lane>>4)*4+reg
                cg[(size_t)(n0 + row) * 1024 + d] = f2bf(acc[rt][ct][rr] + bcv);
            }
    }
}

// ---------------------------------------------------------------------------
// k3: fused GEMM + leaky + gate + LayerNorm.  ZERO-LDS K-loop.
// Block = 64 rows x full D=1024. 512 threads = 8 waves; wave w: cols [w*128,+128).
// Fragments loaded straight from global:
//   B: Wf row (w*128+ct*16+cl), 16B at k-offset q*8   (L2-resident, 1 MB)
//   A: inp row (m0+rt*16+cl),   32B fp32 at q*8 -> cvt_pk to bf16 in-reg
//      (same 8 KB/iter for all 8 waves -> L1 serves 7/8 of the reads)
// Fully unrolled: all offsets are compile-time immediates; compiler
// software-pipelines loads across iterations. No __syncthreads until LN.
// ---------------------------------------------------------------------------
__global__ __launch_bounds__(512, 2) void feat_kernel(
    const float* __restrict__ inp,          // [65536, 512] fp32
    const unsigned short* __restrict__ Wf,  // bf16 [1024, 512]
    const float* __restrict__ b_feat,       // [1024]
    const unsigned short* __restrict__ cg,  // bf16 [2048, 1024]
    const float* __restrict__ gamma,
    const float* __restrict__ beta,
    float* __restrict__ out)                // [65536, 1024] fp32
{
    __shared__ float red1[512];   // [8 waves][64 rows]
    __shared__ float red2[512];
    __shared__ float smu[64];
    __shared__ float srs[64];

    const int t    = threadIdx.x;
    const int lane = t & 63;
    const int w    = t >> 6;            // wave 0..7
    const int cl   = lane & 15;
    const int q    = lane >> 4;
    const int m0   = blockIdx.x << 6;
    const int n0   = m0 & 2047;         // 2048 % 64 == 0: block never crosses b

    f32x4 acc[4][8];
    #pragma unroll
    for (int rt = 0; rt < 4; ++rt)
        #pragma unroll
        for (int ct = 0; ct < 8; ++ct) acc[rt][ct] = (f32x4)0.f;

    // A: lane (cl,q) covers row m0 + rt*16 + cl, k = kb*32 + q*8 .. +7 (fp32)
    const float* ap = inp + (size_t)(m0 + cl) * 512 + (q << 3);
    // B: lane (cl,q) covers Wf row w*128 + ct*16 + cl, same k slice (bf16)
    const unsigned short* bp = Wf + (size_t)((w << 7) + cl) * 512 + (q << 3);

    #pragma unroll
    for (int kb = 0; kb < 16; ++kb) {
        const int k0 = kb << 5;
        short8 a[4];
        #pragma unroll
        for (int rt = 0; rt < 4; ++rt) {
            const float* r = ap + (size_t)(rt << 4) * 512 + k0;
            float4 lo = *(const float4*)(r);
            float4 hi = *(const float4*)(r + 4);
            unsigned p0, p1, p2, p3;
            asm("v_cvt_pk_bf16_f32 %0, %1, %2" : "=v"(p0) : "v"(lo.x), "v"(lo.y));
            asm("v_cvt_pk_bf16_f32 %0, %1, %2" : "=v"(p1) : "v"(lo.z), "v"(lo.w));
            asm("v_cvt_pk_bf16_f32 %0, %1, %2" : "=v"(p2) : "v"(hi.x), "v"(hi.y));
            asm("v_cvt_pk_bf16_f32 %0, %1, %2" : "=v"(p3) : "v"(hi.z), "v"(hi.w));
            union { unsigned u[4]; short8 s; } cv;
            cv.u[0] = p0; cv.u[1] = p1; cv.u[2] = p2; cv.u[3] = p3;
            a[rt] = cv.s;
        }
        #pragma unroll
        for (int ct = 0; ct < 8; ++ct) {
            short8 bf8 = *(const short8*)(bp + (size_t)(ct << 4) * 512 + k0);
            #pragma unroll
            for (int rt = 0; rt < 4; ++rt)
                acc[rt][ct] = __builtin_amdgcn_mfma_f32_16x16x32_bf16(a[rt], bf8, acc[rt][ct], 0, 0, 0);
        }
    }

    // ---- epilogue: bias + leaky + gate, LN stats, normalize, store ----
    float bfv[8];
    #pragma unroll
    for (int ct = 0; ct < 8; ++ct) bfv[ct] = b_feat[(w << 7) + (ct << 4) + cl];

    #pragma unroll
    for (int rt = 0; rt < 4; ++rt) {
        #pragma unroll
        for (int rr = 0; rr < 4; ++rr) {
            const int row = (rt << 4) + (q << 2) + rr;
            float s1 = 0.f, s2 = 0.f;
            #pragma unroll
            for (int ct = 0; ct < 8; ++ct) {
                const int d = (w << 7) + (ct << 4) + cl;
                float x = acc[rt][ct][rr] + bfv[ct];
                x = (x >= 0.f) ? x : 0.2f * x;
                x *= b2f(cg[(size_t)(n0 + row) * 1024 + d]);
                acc[rt][ct][rr] = x;
                s1 += x;
                s2 += x * x;
            }
            #pragma unroll
            for (int off = 1; off < 16; off <<= 1) {
                s1 += __shfl_xor(s1, off, 64);
                s2 += __shfl_xor(s2, off, 64);
            }
            if (cl == 0) {
                red1[(w << 6) + row] = s1;
                red2[(w << 6) + row] = s2;
            }
        }
    }
    __syncthreads();
    if (t < 64) {
        float a = 0.f, bb = 0.f;
        #pragma unroll
        for (int j = 0; j < 8; ++j) { a += red1[(j << 6) + t]; bb += red2[(j << 6) + t]; }
        const float mu  = a * (1.0f / 1024.0f);
        const float var = bb * (1.0f / 1024.0f) - mu * mu;
        smu[t] = mu;
        srs[t] = rsqrtf(var + 1e-5f);
    }
    __syncthreads();

    #pragma unroll
    for (int ct = 0; ct < 8; ++ct) {
        const int d = (w << 7) + (ct << 4) + cl;
        const float g = gamma[d], be = beta[d];
        #pragma unroll
        for (int rt = 0; rt < 4; ++rt) {
            #pragma unroll
            for (int rr = 0; rr < 4; ++rr) {
                const int row = (rt << 4) + (q << 2) + rr;
                out[(size_t)(m0 + row) * 1024 + d] =
                    (acc[rt][ct][rr] - smu[row]) * srs[row] * g + be;
            }
        }
    }
}

// ---------------------------------------------------------------------------
extern "C" void kernel_launch(void* const* d_in, const int* in_sizes, int n_in,
                              void* d_out, int out_size, void* d_ws, size_t ws_size,
                              hipStream_t stream) {
    const float* inp   = (const float*)d_in[0];   // [32,2048,512]
    const float* st    = (const float*)d_in[1];   // [2048,256]
    const float* Wf    = (const float*)d_in[2];   // [1024,512]
    const float* bfeat = (const float*)d_in[3];   // [1024]
    const float* Wc    = (const float*)d_in[4];   // [1024,256]
    const float* bc    = (const float*)d_in[5];   // [1024]
    const float* gamma = (const float*)d_in[6];   // [1024]
    const float* beta  = (const float*)d_in[7];   // [1024]
    float* out = (float*)d_out;

    unsigned short* wsWf = (unsigned short*)d_ws;                      // 1 MB bf16 W_feat
    unsigned short* wsC  = (unsigned short*)((char*)d_ws + (1 << 20)); // 4 MB bf16 c

    convw_kernel<<<512, 256, 0, stream>>>(Wf, wsWf);
    city_kernel<<<dim3(32, 8), 256, 0, stream>>>(st, Wc, bc, wsC);
    feat_kernel<<<1024, 512, 0, stream>>>(inp, wsWf, bfeat, wsC, gamma, beta, out);
}

// Round 2
// 486.234 us; speedup vs baseline: 1.2754x; 1.2754x over previous
//
#include <hip/hip_runtime.h>
#include <hip/hip_bf16.h>

// ---------------------------------------------------------------------------
// Feature_Decoder: out = LN(leaky_relu(inp @ Wf^T + bf) * (static @ Wc^T + bc))
// B=32, N=2048, F=512, K_city=256, D=1024.  M = B*N = 65536.
//   k1 convw: W_feat fp32 -> bf16 in MFMA-fragment order Wr[kb][row][32]
//   k2 city : c = static @ Wc^T + bc, MFMA bf16, store bf16 (ws, 4 MB)
//   k3 feat : 64-row x full-D block, 1024 thr = 16 waves, wave = 64x64 tile
//             (acc[4][4] = 64 regs -> 4 waves/SIMD occupancy).
//             A staged once in LDS (stride-520, minimal bank aliasing);
//             B read direct from L2-resident Wr with 1-deep register dbuf;
//             K-loop has ZERO barriers; fused bias+leaky+gate+LN epilogue.
// ---------------------------------------------------------------------------

typedef __attribute__((ext_vector_type(8))) short short8;
typedef __attribute__((ext_vector_type(4))) float f32x4;

__device__ __forceinline__ unsigned short f2bf(float f) {
    unsigned int u = __float_as_uint(f);
    return (unsigned short)((u + 0x7FFFu + ((u >> 16) & 1u)) >> 16);   // RNE
}
__device__ __forceinline__ float b2f(unsigned short h) {
    return __uint_as_float(((unsigned int)h) << 16);
}

// ---------------------------------------------------------------------------
// k1: W_feat [1024,512] fp32 -> bf16, scattered to Wr[kb][row][32]:
//     dst(row,k) = (k>>5)*32768 + row*32 + (k&31)   (shorts)
// ---------------------------------------------------------------------------
__global__ __launch_bounds__(256) void convw_kernel(
    const float* __restrict__ w, unsigned short* __restrict__ o)
{
    int gid = blockIdx.x * 256 + threadIdx.x;
    int idx = gid * 4;                 // flat element index (row*512 + k)
    int row = idx >> 9;
    int k   = idx & 511;
    float4 v = *(const float4*)(w + idx);
    uint2 p;
    p.x = (unsigned)f2bf(v.x) | ((unsigned)f2bf(v.y) << 16);
    p.y = (unsigned)f2bf(v.z) | ((unsigned)f2bf(v.w) << 16);
    int dst = ((k >> 5) << 15) + (row << 5) + (k & 31);   // 4 k stay in one kb
    *(uint2*)(o + dst) = p;
}

// ---------------------------------------------------------------------------
// k2: c[n,d] = dot(static[n,:], Wc[d,:]) + bc[d]  via MFMA bf16. (unchanged)
// ---------------------------------------------------------------------------
__global__ __launch_bounds__(256) void city_kernel(
    const float* __restrict__ st,    // [2048,256]
    const float* __restrict__ Wc,    // [1024,256]
    const float* __restrict__ bc,    // [1024]
    unsigned short* __restrict__ cg) // bf16 [2048,1024]
{
    __shared__ __align__(16) unsigned short Sa[64 * 264];
    __shared__ __align__(16) unsigned short Sb[128 * 264];
    const int t  = threadIdx.x;
    const int n0 = blockIdx.x << 6;
    const int d0 = blockIdx.y << 7;

    #pragma unroll
    for (int i = 0; i < 16; ++i) {
        int idx = (i << 8) + t;
        int row = idx >> 6, kq = (idx & 63) << 2;
        float4 v = *(const float4*)(st + (size_t)(n0 + row) * 256 + kq);
        uint2 p;
        p.x = (unsigned)f2bf(v.x) | ((unsigned)f2bf(v.y) << 16);
        p.y = (unsigned)f2bf(v.z) | ((unsigned)f2bf(v.w) << 16);
        *(uint2*)(Sa + row * 264 + kq) = p;
    }
    #pragma unroll
    for (int i = 0; i < 32; ++i) {
        int idx = (i << 8) + t;
        int row = idx >> 6, kq = (idx & 63) << 2;
        float4 v = *(const float4*)(Wc + (size_t)(d0 + row) * 256 + kq);
        uint2 p;
        p.x = (unsigned)f2bf(v.x) | ((unsigned)f2bf(v.y) << 16);
        p.y = (unsigned)f2bf(v.z) | ((unsigned)f2bf(v.w) << 16);
        *(uint2*)(Sb + row * 264 + kq) = p;
    }
    __syncthreads();

    const int wv = t >> 6;
    const int cl = t & 15, q = (t >> 4) & 3;
    f32x4 acc[4][2];
    #pragma unroll
    for (int rt = 0; rt < 4; ++rt)
        #pragma unroll
        for (int ct = 0; ct < 2; ++ct) acc[rt][ct] = (f32x4)0.f;

    #pragma unroll
    for (int ks = 0; ks < 8; ++ks) {
        short8 a[4];
        #pragma unroll
        for (int rt = 0; rt < 4; ++rt)
            a[rt] = *(const short8*)(Sa + ((rt << 4) + cl) * 264 + (ks << 5) + (q << 3));
        #pragma unroll
        for (int ct = 0; ct < 2; ++ct) {
            short8 bf8 = *(const short8*)(Sb + ((wv << 5) + (ct << 4) + cl) * 264 + (ks << 5) + (q << 3));
            #pragma unroll
            for (int rt = 0; rt < 4; ++rt)
                acc[rt][ct] = __builtin_amdgcn_mfma_f32_16x16x32_bf16(a[rt], bf8, acc[rt][ct], 0, 0, 0);
        }
    }
    #pragma unroll
    for (int ct = 0; ct < 2; ++ct) {
        const int d = d0 + (wv << 5) + (ct << 4) + cl;
        const float bcv = bc[d];
        #pragma unroll
        for (int rt = 0; rt < 4; ++rt)
            #pragma unroll
            for (int rr = 0; rr < 4; ++rr) {
                const int row = (rt << 4) + (q << 2) + rr;
                cg[(size_t)(n0 + row) * 1024 + d] = f2bf(acc[rt][ct][rr] + bcv);
            }
    }
}

// ---------------------------------------------------------------------------
// k3: fused GEMM + leaky + gate + LayerNorm.
// 1024 threads = 16 waves. Wave w owns rows [0,64) x cols [w*64, w*64+64).
// acc[4][4] = 64 regs; B register-double-buffered from L2; A from LDS.
// ---------------------------------------------------------------------------
__global__ __launch_bounds__(1024, 4) void feat_kernel(
    const float* __restrict__ inp,          // [65536, 512] fp32
    const unsigned short* __restrict__ Wr,  // bf16 Wr[16][1024][32]
    const float* __restrict__ b_feat,       // [1024]
    const unsigned short* __restrict__ cg,  // bf16 [2048, 1024]
    const float* __restrict__ gamma,
    const float* __restrict__ beta,
    float* __restrict__ out)                // [65536, 1024] fp32
{
    __shared__ __align__(16) unsigned short As[64 * 520];  // 65 KB, stride 520
    __shared__ float red1[16 * 64];
    __shared__ float red2[16 * 64];
    __shared__ float smu[64];
    __shared__ float srs[64];

    const int t    = threadIdx.x;
    const int lane = t & 63;
    const int w    = t >> 6;            // wave 0..15 = column strip
    const int cl   = lane & 15;
    const int q    = lane >> 4;
    const int m0   = blockIdx.x << 6;
    const int n0   = m0 & 2047;         // 2048 % 64 == 0: block never crosses b

    f32x4 acc[4][4];
    #pragma unroll
    for (int rt = 0; rt < 4; ++rt)
        #pragma unroll
        for (int ct = 0; ct < 4; ++ct) acc[rt][ct] = (f32x4)0.f;

    // B: Wr offset (shorts) for (kb, ct) = kb*32768 + (w*64+ct*16+cl)*32 + q*8
    const unsigned short* bp = Wr + ((((w << 6) + cl) << 5) + (q << 3));

    // prologue: B frags for kb=0 (in flight during A staging)
    short8 bc[4], bn[4];
    #pragma unroll
    for (int ct = 0; ct < 4; ++ct)
        bc[ct] = *(const short8*)(bp + (ct << 9));

    // ---- A stage: 64 rows x 512 k fp32 -> bf16 LDS, once ----
    // thread handles 8 float4s at flat float4-index j*1024 + t (coalesced)
    {
        const float* ag = inp + (size_t)m0 * 512;
        #pragma unroll
        for (int j = 0; j < 8; ++j) {
            int g = (j << 10) + t;            // float4 index in 64x512 tile
            float4 v = *(const float4*)(ag + ((size_t)g << 2));
            int row = g >> 7, c4 = g & 127;   // row, 4-float chunk within row
            uint2 p;
            p.x = (unsigned)f2bf(v.x) | ((unsigned)f2bf(v.y) << 16);
            p.y = (unsigned)f2bf(v.z) | ((unsigned)f2bf(v.w) << 16);
            *(uint2*)(&As[row * 520 + (c4 << 2)]) = p;
        }
    }
    __syncthreads();

    // ---- barrier-free K-loop ----
    const int abase = cl * 520 + (q << 3);
    #pragma unroll
    for (int kb = 0; kb < 16; ++kb) {
        if (kb < 15) {
            #pragma unroll
            for (int ct = 0; ct < 4; ++ct)
                bn[ct] = *(const short8*)(bp + ((kb + 1) << 15) + (ct << 9));
        }
        short8 a[4];
        #pragma unroll
        for (int rt = 0; rt < 4; ++rt)
            a[rt] = *(const short8*)(&As[abase + rt * (16 * 520) + (kb << 5)]);
        #pragma unroll
        for (int ct = 0; ct < 4; ++ct)
            #pragma unroll
            for (int rt = 0; rt < 4; ++rt)
                acc[rt][ct] = __builtin_amdgcn_mfma_f32_16x16x32_bf16(a[rt], bc[ct], acc[rt][ct], 0, 0, 0);
        if (kb < 15) {
            #pragma unroll
            for (int ct = 0; ct < 4; ++ct) bc[ct] = bn[ct];
        }
    }

    // ---- epilogue: bias + leaky + gate, LN stats, normalize, store ----
    float bfv[4];
    #pragma unroll
    for (int ct = 0; ct < 4; ++ct) bfv[ct] = b_feat[(w << 6) + (ct << 4) + cl];

    #pragma unroll
    for (int rt = 0; rt < 4; ++rt) {
        #pragma unroll
        for (int rr = 0; rr < 4; ++rr) {
            const int row = (rt << 4) + (q << 2) + rr;
            float s1 = 0.f, s2 = 0.f;
            #pragma unroll
            for (int ct = 0; ct < 4; ++ct) {
                const int d = (w << 6) + (ct << 4) + cl;
                float x = acc[rt][ct][rr] + bfv[ct];
                x = (x >= 0.f) ? x : 0.2f * x;
                x *= b2f(cg[(size_t)(n0 + row) * 1024 + d]);
                acc[rt][ct][rr] = x;
                s1 += x;
                s2 += x * x;
            }
            #pragma unroll
            for (int off = 1; off < 16; off <<= 1) {
                s1 += __shfl_xor(s1, off, 64);
                s2 += __shfl_xor(s2, off, 64);
            }
            if (cl == 0) {
                red1[(w << 6) + row] = s1;
                red2[(w << 6) + row] = s2;
            }
        }
    }
    __syncthreads();
    if (t < 64) {
        float a = 0.f, bb = 0.f;
        #pragma unroll
        for (int j = 0; j < 16; ++j) { a += red1[(j << 6) + t]; bb += red2[(j << 6) + t]; }
        const float mu  = a * (1.0f / 1024.0f);
        const float var = bb * (1.0f / 1024.0f) - mu * mu;
        smu[t] = mu;
        srs[t] = rsqrtf(var + 1e-5f);
    }
    __syncthreads();

    #pragma unroll
    for (int ct = 0; ct < 4; ++ct) {
        const int d = (w << 6) + (ct << 4) + cl;
        const float g = gamma[d], be = beta[d];
        #pragma unroll
        for (int rt = 0; rt < 4; ++rt) {
            #pragma unroll
            for (int rr = 0; rr < 4; ++rr) {
                const int row = (rt << 4) + (q << 2) + rr;
                __builtin_nontemporal_store(
                    (acc[rt][ct][rr] - smu[row]) * srs[row] * g + be,
                    &out[(size_t)(m0 + row) * 1024 + d]);
            }
        }
    }
}

// ---------------------------------------------------------------------------
extern "C" void kernel_launch(void* const* d_in, const int* in_sizes, int n_in,
                              void* d_out, int out_size, void* d_ws, size_t ws_size,
                              hipStream_t stream) {
    const float* inp   = (const float*)d_in[0];   // [32,2048,512]
    const float* st    = (const float*)d_in[1];   // [2048,256]
    const float* Wf    = (const float*)d_in[2];   // [1024,512]
    const float* bfeat = (const float*)d_in[3];   // [1024]
    const float* Wc    = (const float*)d_in[4];   // [1024,256]
    const float* bc    = (const float*)d_in[5];   // [1024]
    const float* gamma = (const float*)d_in[6];   // [1024]
    const float* beta  = (const float*)d_in[7];   // [1024]
    float* out = (float*)d_out;

    unsigned short* wsWr = (unsigned short*)d_ws;                      // 1 MB bf16 Wr
    unsigned short* wsC  = (unsigned short*)((char*)d_ws + (1 << 20)); // 4 MB bf16 c

    convw_kernel<<<512, 256, 0, stream>>>(Wf, wsWr);
    city_kernel<<<dim3(32, 8), 256, 0, stream>>>(st, Wc, bc, wsC);
    feat_kernel<<<1024, 1024, 0, stream>>>(inp, wsWr, bfeat, wsC, gamma, beta, out);
}